// Round 2
// baseline (1017.702 us; speedup 1.0000x reference)
//
#include <hip/hip_runtime.h>

typedef float f32x4  __attribute__((ext_vector_type(4)));
typedef float f32x16 __attribute__((ext_vector_type(16)));
typedef int   i32x4  __attribute__((ext_vector_type(4)));
typedef int   i32x8  __attribute__((ext_vector_type(8)));

#define AS1 __attribute__((address_space(1)))
#define AS3 __attribute__((address_space(3)))

// ---------------------------------------------------------------------------
// Kernel 1 (R1, proven): per-token quant of x -> fp8 e4m3 + scale
// ---------------------------------------------------------------------------
__global__ __launch_bounds__(256) void quant_x_fp8_kernel(
    const float* __restrict__ x, unsigned char* __restrict__ x8,
    float* __restrict__ xs, int K) {
  int m = blockIdx.x;
  int t = threadIdx.x;
  const f32x4* src = (const f32x4*)(x + (size_t)m * K + t * 16);
  f32x4 v[4];
  float am = 0.0f;
#pragma unroll
  for (int i = 0; i < 4; ++i) {
    v[i] = src[i];
#pragma unroll
    for (int j = 0; j < 4; ++j) am = fmaxf(am, __builtin_fabsf(v[i][j]));
  }
#pragma unroll
  for (int off = 32; off >= 1; off >>= 1)
    am = fmaxf(am, __shfl_xor(am, off, 64));
  __shared__ float red[4];
  int wv = t >> 6, lane = t & 63;
  if (lane == 0) red[wv] = am;
  __syncthreads();
  am = fmaxf(fmaxf(red[0], red[1]), fmaxf(red[2], red[3]));
  am = fmaxf(am, 1e-12f);
  float sc = am / 448.0f;
  if (t == 0) xs[m] = sc;
  i32x4 out;
#pragma unroll
  for (int i = 0; i < 4; ++i) {
    float q0 = v[i][0] / sc, q1 = v[i][1] / sc;
    float q2 = v[i][2] / sc, q3 = v[i][3] / sc;
    int p = __builtin_amdgcn_cvt_pk_fp8_f32(q0, q1, 0, false);
    p = __builtin_amdgcn_cvt_pk_fp8_f32(q2, q3, p, true);
    out[i] = p;
  }
  *(i32x4*)(x8 + (size_t)m * K + t * 16) = out;
}

// ---------------------------------------------------------------------------
// Kernel 2 (R1, proven): weight f32 (fp8-representable) -> fp8 bytes
// ---------------------------------------------------------------------------
__global__ __launch_bounds__(256) void quant_w_fp8_kernel(
    const float* __restrict__ w, unsigned char* __restrict__ w8) {
  size_t idx = (size_t)blockIdx.x * 256 + threadIdx.x;
  const f32x4* src = (const f32x4*)w + idx * 4;
  i32x4 out;
#pragma unroll
  for (int i = 0; i < 4; ++i) {
    f32x4 v = src[i];
    int p = __builtin_amdgcn_cvt_pk_fp8_f32(v[0], v[1], 0, false);
    p = __builtin_amdgcn_cvt_pk_fp8_f32(v[2], v[3], p, true);
    out[i] = p;
  }
  ((i32x4*)w8)[idx] = out;
}

// ---------------------------------------------------------------------------
// Kernel 3: MX-fp8 GEMM. R13 structure (math validated R13: absmax 0.0625)
// + R14 fix: __launch_bounds__(512, 1).
// R13 post-mortem: launch_bounds(512,2) made the allocator budget for
// 16 waves/CU -> 128-VGPR cap -> 128-VGPR acc spilled (FETCH 1.3GB,
// WRITE 1.9GB scratch, MfmaUtil 5.4%). LDS=128KB already caps us at
// 1 block/CU (8 waves, 2/SIMD), so the correct reg budget is 256/wave.
// Block tile 256(M)x256(N), K-tile 128 (= scale block). 8 waves 2(wr)x4(wc);
// per-wave output 128x64 = 4mj x 2nj of 32x32 frags -> acc 128 VGPR
// (+ bf 32 + af 16 + temps/addr ~50 ~= 230 <= 256: fits, no spill).
// LDS: 2 bufs x 64KB {A: 256 rows x 128B = 32KB @0, B: 32KB @+32768};
// buf0 @0, buf1 @65536.
// Swizzle (validated R11): 16B slot s at row r stored s^(r&7); inverse
// pre-applied on global source (rule #21).
// 8 phases / 2 K-tiles, one mj per phase in order {0,2,1,3} so A sweeps
// {0,2} (rows 0-63,128-191) are last-read at P2 and {1,3} at P3.
// Stage slots (2 gloads/thread each), all >=1 closing-barrier after the
// region's last consuming read:
//   P0: A(T+1)sw13->buf1 (last read prev P7) | P1: B(T+2)01->buf0 (P0)
//   P2: B(T+2)23->buf0 (P0)                  | P3: A(T+2)sw02->buf0 (P2)
//   P4: A(T+2)sw13->buf0 (P3)                | P5: B(T+3)01->buf1 (P4)
//   P6: B(T+3)23->buf1 (P4)                  | P7: A(T+3)sw02->buf1 (P6)
// Waits (counted, in-order vmcnt): end-P0 vmcnt(8) -> prev-P4 A(T)13 done
// before P1 reads; end-P3 vmcnt(6) -> P0's A(T+1)13 done before P5 (and
// prev-P7 A(T+1)02 before P4); end-P7 vmcnt(8) -> P1..P3 (B,A02 of T+2)
// done before next P0. Every prefetch gets 3-4 phases of cover.
// ---------------------------------------------------------------------------
__global__ __launch_bounds__(512, 1) void gemm_mxfp8_kernel(
    const unsigned char* __restrict__ A8,   // [M][K] fp8
    const unsigned char* __restrict__ W8,   // [N][K] fp8
    const float* __restrict__ xs,           // [M]
    const float* __restrict__ wsinv,        // [N/128][K/128]
    float* __restrict__ Y,                  // [M][N] f32
    int M, int N, int K) {
  const int KB = K >> 7;  // K/128 tiles (32)

  int bid = blockIdx.x, nwg = gridDim.x;
  int wg = (bid & 7) * (nwg >> 3) + (bid >> 3);
  int mt = M >> 8;                  // 16
  int bm = wg & (mt - 1);
  int bn = wg / mt;                 // 0..31
  int m0 = bm << 8, n0 = bn << 8;   // 256 x 256 tile

  __shared__ __align__(16) char lds[131072];

  const int tid = threadIdx.x, wv = tid >> 6, lane = tid & 63;
  const int wr = wv >> 2, wc = wv & 3;          // 2 x 4 wave grid
  const int l31 = lane & 31, hi2 = lane >> 5;
  const int salt = l31 & 7;

  // fragment addressing (within a buf: A at 0, B at +32768)
  const int aRow = (wr * 128 + l31) * 128;
  const int bRow = 32768 + (wc * 64 + l31) * 128;
  const int sL0 = ((hi2 * 2 + 0) ^ salt) << 4;       // ks=0, k-low 16B
  const int sH0 = ((hi2 * 2 + 1) ^ salt) << 4;       // ks=0, k-high
  const int sL1 = ((4 + hi2 * 2 + 0) ^ salt) << 4;   // ks=1
  const int sH1 = ((4 + hi2 * 2 + 1) ^ salt) << 4;

  // staging: dest = region + sweep*8192 + tid*16 (linear, 64 rows/sweep);
  // source row = sweep*64 + (tid>>3); col pre-swizzled (involution).
  const int stgD = tid << 4;
  const int rIdx = tid >> 3;
  const int cSrc = ((tid & 7) ^ ((tid >> 3) & 7)) << 4;
  const size_t rowB = (size_t)K;  // fp8: 1 byte/elem
  const size_t g64 = 64 * rowB;
  const char* pA = (const char*)A8 + (size_t)(m0 + rIdx) * rowB + cSrc;
  const char* pB = (const char*)W8 + (size_t)(n0 + rIdx) * rowB + cSrc;

  // scale row: N-tile 256 spans 2 scale rows; wc 0,1 -> row bn*2, wc 2,3 -> +1
  const float* wsv = wsinv + (size_t)(bn * 2 + (wc >> 1)) * KB;

  f32x16 acc[4][2];
#pragma unroll
  for (int i = 0; i < 4; ++i)
#pragma unroll
    for (int j = 0; j < 2; ++j) acc[i][j] = (f32x16)0.0f;

  i32x8 af[2], bf[2][2];

#define GL(SRC, DST)                                                           \
  __builtin_amdgcn_global_load_lds((const AS1 void*)(SRC), (AS3 void*)(DST),   \
                                   16, 0, 0)
// A sweeps 0,2 (rows 0-63 / 128-191)
#define STG_A02(COND, BASE, TT)                                                \
  if (COND) {                                                                  \
    const char* s_ = pA + (size_t)(TT)*128;                                    \
    char* d_ = lds + (BASE) + stgD;                                            \
    GL(s_, d_);                                                                \
    GL(s_ + 2 * g64, d_ + 16384);                                              \
  }
// A sweeps 1,3 (rows 64-127 / 192-255)
#define STG_A13(COND, BASE, TT)                                                \
  if (COND) {                                                                  \
    const char* s_ = pA + (size_t)(TT)*128 + g64;                              \
    char* d_ = lds + (BASE) + 8192 + stgD;                                     \
    GL(s_, d_);                                                                \
    GL(s_ + 2 * g64, d_ + 16384);                                              \
  }
// B sweeps 0,1 (rows 0-127)
#define STG_B01(COND, BASE, TT)                                                \
  if (COND) {                                                                  \
    const char* s_ = pB + (size_t)(TT)*128;                                    \
    char* d_ = lds + (BASE) + 32768 + stgD;                                    \
    GL(s_, d_);                                                                \
    GL(s_ + g64, d_ + 8192);                                                   \
  }
// B sweeps 2,3 (rows 128-255)
#define STG_B23(COND, BASE, TT)                                                \
  if (COND) {                                                                  \
    const char* s_ = pB + (size_t)(TT)*128 + 2 * g64;                          \
    char* d_ = lds + (BASE) + 32768 + 16384 + stgD;                            \
    GL(s_, d_);                                                                \
    GL(s_ + g64, d_ + 8192);                                                   \
  }

// A frags for one mj (both ksteps): 4 ds_read_b128 -> af[2]
#define RD_A(BUFB, MJ)                                                         \
  {                                                                            \
    const char* p_ = lds + (BUFB) + aRow + (MJ)*4096;                          \
    i32x4 lo0 = *(const i32x4*)(p_ + sL0);                                     \
    i32x4 hi0 = *(const i32x4*)(p_ + sH0);                                     \
    i32x4 lo1 = *(const i32x4*)(p_ + sL1);                                     \
    i32x4 hi1 = *(const i32x4*)(p_ + sH1);                                     \
    af[0] = __builtin_shufflevector(lo0, hi0, 0, 1, 2, 3, 4, 5, 6, 7);         \
    af[1] = __builtin_shufflevector(lo1, hi1, 0, 1, 2, 3, 4, 5, 6, 7);         \
  }
// all B frags (nj 0..1 x ks 0..1): 8 ds_read_b128
#define RD_B(BUFB)                                                             \
  _Pragma("unroll") for (int nj = 0; nj < 2; ++nj) {                           \
    const char* p_ = lds + (BUFB) + bRow + nj * 4096;                          \
    i32x4 lo0 = *(const i32x4*)(p_ + sL0);                                     \
    i32x4 hi0 = *(const i32x4*)(p_ + sH0);                                     \
    i32x4 lo1 = *(const i32x4*)(p_ + sL1);                                     \
    i32x4 hi1 = *(const i32x4*)(p_ + sH1);                                     \
    bf[nj][0] = __builtin_shufflevector(lo0, hi0, 0, 1, 2, 3, 4, 5, 6, 7);     \
    bf[nj][1] = __builtin_shufflevector(lo1, hi1, 0, 1, 2, 3, 4, 5, 6, 7);     \
  }

// 4 MFMA (2 nj x ks-chain) + fold by SV into acc[MJ][*]
#define MMF(MJ, SV)                                                            \
  _Pragma("unroll") for (int nj = 0; nj < 2; ++nj) {                           \
    f32x16 t_ = __builtin_amdgcn_mfma_scale_f32_32x32x64_f8f6f4(               \
        af[0], bf[nj][0], (f32x16)0.0f, 0, 0, 0, 0x7f7f7f7f, 0, 0x7f7f7f7f);   \
    t_ = __builtin_amdgcn_mfma_scale_f32_32x32x64_f8f6f4(                      \
        af[1], bf[nj][1], t_, 0, 0, 0, 0x7f7f7f7f, 0, 0x7f7f7f7f);             \
    _Pragma("unroll") for (int q = 0; q < 16; ++q)                             \
        acc[MJ][nj][q] = __builtin_fmaf(SV, t_[q], acc[MJ][nj][q]);            \
  }

#define PH(RD, ST, MM_)                                                        \
  {                                                                            \
    RD;                                                                        \
    ST;                                                                        \
    __builtin_amdgcn_s_barrier();                                              \
    __builtin_amdgcn_s_setprio(1);                                             \
    MM_;                                                                       \
    __builtin_amdgcn_s_setprio(0);                                             \
    __builtin_amdgcn_s_barrier();                                              \
  }
#define PHW(RD, ST, MM_, VM)                                                   \
  {                                                                            \
    RD;                                                                        \
    ST;                                                                        \
    __builtin_amdgcn_s_barrier();                                              \
    __builtin_amdgcn_s_setprio(1);                                             \
    MM_;                                                                       \
    __builtin_amdgcn_s_setprio(0);                                             \
    asm volatile("s_waitcnt " VM ::: "memory");                                \
    __builtin_amdgcn_s_barrier();                                              \
  }

  // prologue: mirror steady invariant. Issue (2 gloads each):
  // B(0)01 B(0)23 A(0)02 A(0)13 B(1)01 B(1)23 A(1)02 = 14 gloads;
  // vmcnt(8) completes B(0)+A(0)02 (needed at P0), leaves
  // {A(0)13, B(1)01, B(1)23, A(1)02} = 8 outstanding = steady entry state.
  STG_B01(true, 0, 0);
  STG_B23(true, 0, 0);
  STG_A02(true, 0, 0);
  STG_A13(true, 0, 0);
  STG_B01(true, 65536, 1);
  STG_B23(true, 65536, 1);
  STG_A02(true, 65536, 1);
  asm volatile("s_waitcnt vmcnt(8)" ::: "memory");
  __builtin_amdgcn_s_barrier();

#define ITER(T, G, V0, V3, V7)                                                 \
  {                                                                            \
    float s0_ = wsv[(T)];                                                      \
    float s1_ = wsv[(T) + 1];                                                  \
    PHW(RD_B(0); RD_A(0, 0), STG_A13(true, 65536, (T) + 1), MMF(0, s0_), V0)   \
    PH(RD_A(0, 2), STG_B01(G, 0, (T) + 2), MMF(2, s0_))                        \
    PH(RD_A(0, 1), STG_B23(G, 0, (T) + 2), MMF(1, s0_))                        \
    PHW(RD_A(0, 3), STG_A02(G, 0, (T) + 2), MMF(3, s0_), V3)                   \
    PH(RD_B(65536); RD_A(65536, 0), STG_A13(G, 0, (T) + 2), MMF(0, s1_))       \
    PH(RD_A(65536, 2), STG_B01(G, 65536, (T) + 3), MMF(2, s1_))                \
    PH(RD_A(65536, 1), STG_B23(G, 65536, (T) + 3), MMF(1, s1_))                \
    PHW(RD_A(65536, 3), STG_A02(G, 65536, (T) + 3), MMF(3, s1_), V7)           \
  }

  for (int t = 0; t < KB - 2; t += 2) {
    ITER(t, true, "vmcnt(8)", "vmcnt(6)", "vmcnt(8)");
  }
  // tail (tiles KB-2, KB-1): only A(KB-1)sw13 staged at P0; drain by P3.
  ITER(KB - 2, false, "vmcnt(8)", "vmcnt(0)", "vmcnt(0)");

#undef ITER
#undef PHW
#undef PH
#undef MMF
#undef RD_B
#undef RD_A
#undef STG_B23
#undef STG_B01
#undef STG_A13
#undef STG_A02
#undef GL

  // epilogue (validated C/D mapping): col=l31, row=q*8+hi2*4+j
#pragma unroll
  for (int mj = 0; mj < 4; ++mj)
#pragma unroll
    for (int nj = 0; nj < 2; ++nj) {
      int col = n0 + wc * 64 + nj * 32 + l31;
#pragma unroll
      for (int q = 0; q < 4; ++q) {
        int row0 = m0 + wr * 128 + mj * 32 + q * 8 + hi2 * 4;
        f32x4 sv = *(const f32x4*)(xs + row0);
#pragma unroll
        for (int j = 0; j < 4; ++j)
          Y[(size_t)(row0 + j) * N + col] = acc[mj][nj][q * 4 + j] * sv[j];
      }
    }
}

// ---------------------------------------------------------------------------
extern "C" void kernel_launch(void* const* d_in, const int* in_sizes, int n_in,
                              void* d_out, int out_size, void* d_ws, size_t ws_size,
                              hipStream_t stream) {
  const float* x     = (const float*)d_in[0];   // [B,S,K] f32
  const float* w     = (const float*)d_in[1];   // [N,K] f32 (fp8-representable)
  const float* wsinv = (const float*)d_in[2];   // [N/128,K/128] f32
  float* y = (float*)d_out;

  const int K = 4096;
  const int M = in_sizes[0] / K;   // 4096
  const int N = in_sizes[1] / K;   // 8192

  unsigned char* x8 = (unsigned char*)d_ws;                       // M*K
  float* xs = (float*)((char*)d_ws + (size_t)M * K);              // M floats
  unsigned char* w8 =
      (unsigned char*)d_ws + (size_t)M * K + (size_t)M * 4;       // N*K

  quant_x_fp8_kernel<<<M, 256, 0, stream>>>(x, x8, xs, K);
  quant_w_fp8_kernel<<<(int)(((size_t)N * K / 16 + 255) / 256), 256, 0,
                       stream>>>(w, w8);

  dim3 grid((M / 256) * (N / 256));  // 512
  gemm_mxfp8_kernel<<<grid, 512, 0, stream>>>(x8, w8, xs, wsinv, y, M, N, K);
}

// Round 3
// 667.648 us; speedup vs baseline: 1.5243x; 1.5243x over previous
//
#include <hip/hip_runtime.h>

typedef float f32x4  __attribute__((ext_vector_type(4)));
typedef float f32x16 __attribute__((ext_vector_type(16)));
typedef int   i32x4  __attribute__((ext_vector_type(4)));
typedef int   i32x8  __attribute__((ext_vector_type(8)));

#define AS1 __attribute__((address_space(1)))
#define AS3 __attribute__((address_space(3)))

// ---------------------------------------------------------------------------
// Kernel 1 (R1, proven): per-token quant of x -> fp8 e4m3 + scale
// ---------------------------------------------------------------------------
__global__ __launch_bounds__(256) void quant_x_fp8_kernel(
    const float* __restrict__ x, unsigned char* __restrict__ x8,
    float* __restrict__ xs, int K) {
  int m = blockIdx.x;
  int t = threadIdx.x;
  const f32x4* src = (const f32x4*)(x + (size_t)m * K + t * 16);
  f32x4 v[4];
  float am = 0.0f;
#pragma unroll
  for (int i = 0; i < 4; ++i) {
    v[i] = src[i];
#pragma unroll
    for (int j = 0; j < 4; ++j) am = fmaxf(am, __builtin_fabsf(v[i][j]));
  }
#pragma unroll
  for (int off = 32; off >= 1; off >>= 1)
    am = fmaxf(am, __shfl_xor(am, off, 64));
  __shared__ float red[4];
  int wv = t >> 6, lane = t & 63;
  if (lane == 0) red[wv] = am;
  __syncthreads();
  am = fmaxf(fmaxf(red[0], red[1]), fmaxf(red[2], red[3]));
  am = fmaxf(am, 1e-12f);
  float sc = am / 448.0f;
  if (t == 0) xs[m] = sc;
  i32x4 out;
#pragma unroll
  for (int i = 0; i < 4; ++i) {
    float q0 = v[i][0] / sc, q1 = v[i][1] / sc;
    float q2 = v[i][2] / sc, q3 = v[i][3] / sc;
    int p = __builtin_amdgcn_cvt_pk_fp8_f32(q0, q1, 0, false);
    p = __builtin_amdgcn_cvt_pk_fp8_f32(q2, q3, p, true);
    out[i] = p;
  }
  *(i32x4*)(x8 + (size_t)m * K + t * 16) = out;
}

// ---------------------------------------------------------------------------
// Kernel 2 (R1, proven): weight f32 (fp8-representable) -> fp8 bytes
// ---------------------------------------------------------------------------
__global__ __launch_bounds__(256) void quant_w_fp8_kernel(
    const float* __restrict__ w, unsigned char* __restrict__ w8) {
  size_t idx = (size_t)blockIdx.x * 256 + threadIdx.x;
  const f32x4* src = (const f32x4*)w + idx * 4;
  i32x4 out;
#pragma unroll
  for (int i = 0; i < 4; ++i) {
    f32x4 v = src[i];
    int p = __builtin_amdgcn_cvt_pk_fp8_f32(v[0], v[1], 0, false);
    p = __builtin_amdgcn_cvt_pk_fp8_f32(v[2], v[3], p, true);
    out[i] = p;
  }
  ((i32x4*)w8)[idx] = out;
}

// ---------------------------------------------------------------------------
// Kernel 3: MX-fp8 GEMM. R15 = R12's PROVEN geometry + 3-deep LDS pipeline.
// R13/R14 post-mortem: 128-VGPR acc (256x256 tile) spills at 512 threads.
// Evidence: acc touched by VALU per phase (scale fold) pins it to the ~128
// arch-VGPR budget; m201's MFMA-only-chained 128-acc doesn't spill. The
// per-K-tile fold is unavoidable (scales vary per k-block) -> 64-acc wave
// tile (R12) is the register-constrained optimum. This round attacks the
// OTHER half of R12's profile: 3470cy/K-tile/CU measured vs ~1900cy modeled
// LDS+MFMA -> ~45% stall; R12's vmcnt(2) gave ~1 phase (~800cy) of load
// cover < HBM miss latency (~900cy).
// Fix: 3 LDS bufs x 48KB = 144KB (<=160KB), stage tile T+2 during tile T,
// steady vmcnt(6) once per K-tile -> ~4 phases (~3000cy) of cover; vmcnt
// never drains in main loop. Registers/math/epilogue identical to R12.
// Geometry: block 256(M)x128(N), K-tile 128 (= scale block), 8 waves
// 4(wr)x2(wc), wave 64x64 -> acc[2][2] f32x16 = 64 VGPR. Buf = {A: 256
// rows x 128B = 32KB @0, B: 128 rows x 128B = 16KB @+32768}; bufs @0,
// @49152, @98304 (tile t uses buf t%3).
// Swizzle (validated): 16B slot s at row r stored s^(r&7); inverse applied
// on global source (rule #21).
// Per K-tile, 2 phases:
//   phaseA: RD_B + RD_A(mj0) | stage A(T+2) | bar | MMF(0) | bar
//   phaseB: RD_A(mj1)        | stage B(T+2) | bar | MMF(1) | vmcnt | bar
// WAR: stage of T+2 hits buf (T+2)%3 = (T-1)%3, whose last consuming MFMA
// was phaseB(T-1); stage is issued >=1 closing-barrier later ✓ (R12 rule).
// Waits: at phaseB(T) end, outstanding = T+1's 6 + T+2's 6; vmcnt(6)
// completes ALL of tile T+1 before tile T+1 reads. Tail (KB-2, KB-1):
// no staging; vmcnt(0) drains.
// ---------------------------------------------------------------------------
__global__ __launch_bounds__(512, 2) void gemm_mxfp8_kernel(
    const unsigned char* __restrict__ A8,   // [M][K] fp8
    const unsigned char* __restrict__ W8,   // [N][K] fp8
    const float* __restrict__ xs,           // [M]
    const float* __restrict__ wsinv,        // [N/128][K/128]
    float* __restrict__ Y,                  // [M][N] f32
    int M, int N, int K) {
  const int KB = K >> 7;  // K/128 tiles (32); code assumes KB % 3 == 2

  int bid = blockIdx.x, nwg = gridDim.x;
  int wg = (bid & 7) * (nwg >> 3) + (bid >> 3);
  int mt = M >> 8;                  // 16
  int bm = wg & (mt - 1);
  int bn = wg / mt;
  int m0 = bm << 8, n0 = bn << 7;   // 256 x 128 tile

  __shared__ __align__(16) char lds[147456];  // 3 x 48KB

  const int tid = threadIdx.x, wv = tid >> 6, lane = tid & 63;
  const int wr = wv >> 1, wc = wv & 1;          // 4 x 2 wave grid
  const int l31 = lane & 31, hi2 = lane >> 5;
  const int salt = l31 & 7;

  // fragment addressing (within a buf: A at 0, B at +32768)
  const int aRow = (wr * 64 + l31) * 128;
  const int bRow = 32768 + (wc * 64 + l31) * 128;
  const int sL0 = ((hi2 * 2 + 0) ^ salt) << 4;       // ks=0, k-low 16B
  const int sH0 = ((hi2 * 2 + 1) ^ salt) << 4;       // ks=0, k-high
  const int sL1 = ((4 + hi2 * 2 + 0) ^ salt) << 4;   // ks=1
  const int sH1 = ((4 + hi2 * 2 + 1) ^ salt) << 4;

  // staging: dest = region + sweep*8192 + tid*16 (linear, 64 rows/sweep);
  // source row = sweep*64 + (tid>>3); col pre-swizzled (involution).
  const int stgD = tid << 4;
  const int rIdx = tid >> 3;
  const int cSrc = ((tid & 7) ^ ((tid >> 3) & 7)) << 4;
  const size_t rowB = (size_t)K;  // fp8: 1 byte/elem
  const size_t g64 = 64 * rowB;
  const char* pA = (const char*)A8 + (size_t)(m0 + rIdx) * rowB + cSrc;
  const char* pB = (const char*)W8 + (size_t)(n0 + rIdx) * rowB + cSrc;

  const float* wsv = wsinv + (size_t)bn * KB;  // block-uniform scale row

  f32x16 acc[2][2];
#pragma unroll
  for (int i = 0; i < 2; ++i)
#pragma unroll
    for (int j = 0; j < 2; ++j) acc[i][j] = (f32x16)0.0f;

  i32x8 af[2], bf[2][2];

#define GL(SRC, DST)                                                           \
  __builtin_amdgcn_global_load_lds((const AS1 void*)(SRC), (AS3 void*)(DST),   \
                                   16, 0, 0)
#define STG_A(COND, ABASE, TT)                                                 \
  if (COND) {                                                                  \
    const char* s_ = pA + (size_t)(TT)*128;                                    \
    char* d_ = lds + (ABASE) + stgD;                                           \
    GL(s_, d_);                                                                \
    GL(s_ + g64, d_ + 8192);                                                   \
    GL(s_ + 2 * g64, d_ + 16384);                                              \
    GL(s_ + 3 * g64, d_ + 24576);                                              \
  }
#define STG_B(COND, BBASE, TT)                                                 \
  if (COND) {                                                                  \
    const char* s_ = pB + (size_t)(TT)*128;                                    \
    char* d_ = lds + (BBASE) + 32768 + stgD;                                   \
    GL(s_, d_);                                                                \
    GL(s_ + g64, d_ + 8192);                                                   \
  }

// A frags for one mj (both ksteps): 4 ds_read_b128 -> af[2]
#define RD_A(BUFB, MJ)                                                         \
  {                                                                            \
    const char* p_ = lds + (BUFB) + aRow + (MJ)*4096;                          \
    i32x4 lo0 = *(const i32x4*)(p_ + sL0);                                     \
    i32x4 hi0 = *(const i32x4*)(p_ + sH0);                                     \
    i32x4 lo1 = *(const i32x4*)(p_ + sL1);                                     \
    i32x4 hi1 = *(const i32x4*)(p_ + sH1);                                     \
    af[0] = __builtin_shufflevector(lo0, hi0, 0, 1, 2, 3, 4, 5, 6, 7);         \
    af[1] = __builtin_shufflevector(lo1, hi1, 0, 1, 2, 3, 4, 5, 6, 7);         \
  }
// all B frags (nj 0..1 x ks 0..1): 8 ds_read_b128
#define RD_B(BUFB)                                                             \
  _Pragma("unroll") for (int nj = 0; nj < 2; ++nj) {                           \
    const char* p_ = lds + (BUFB) + bRow + nj * 4096;                          \
    i32x4 lo0 = *(const i32x4*)(p_ + sL0);                                     \
    i32x4 hi0 = *(const i32x4*)(p_ + sH0);                                     \
    i32x4 lo1 = *(const i32x4*)(p_ + sL1);                                     \
    i32x4 hi1 = *(const i32x4*)(p_ + sH1);                                     \
    bf[nj][0] = __builtin_shufflevector(lo0, hi0, 0, 1, 2, 3, 4, 5, 6, 7);     \
    bf[nj][1] = __builtin_shufflevector(lo1, hi1, 0, 1, 2, 3, 4, 5, 6, 7);     \
  }

// 4 MFMA (2 nj x ks-chain) + fold by SV into acc[MJ][*]
#define MMF(MJ, SV)                                                            \
  _Pragma("unroll") for (int nj = 0; nj < 2; ++nj) {                           \
    f32x16 t_ = __builtin_amdgcn_mfma_scale_f32_32x32x64_f8f6f4(               \
        af[0], bf[nj][0], (f32x16)0.0f, 0, 0, 0, 0x7f7f7f7f, 0, 0x7f7f7f7f);   \
    t_ = __builtin_amdgcn_mfma_scale_f32_32x32x64_f8f6f4(                      \
        af[1], bf[nj][1], t_, 0, 0, 0, 0x7f7f7f7f, 0, 0x7f7f7f7f);             \
    _Pragma("unroll") for (int q = 0; q < 16; ++q)                             \
        acc[MJ][nj][q] = __builtin_fmaf(SV, t_[q], acc[MJ][nj][q]);            \
  }

#define PH(RD, ST, MM_)                                                        \
  {                                                                            \
    RD;                                                                        \
    ST;                                                                        \
    __builtin_amdgcn_s_barrier();                                              \
    __builtin_amdgcn_s_setprio(1);                                             \
    MM_;                                                                       \
    __builtin_amdgcn_s_setprio(0);                                             \
    __builtin_amdgcn_s_barrier();                                              \
  }
#define PHW(RD, ST, MM_, VM)                                                   \
  {                                                                            \
    RD;                                                                        \
    ST;                                                                        \
    __builtin_amdgcn_s_barrier();                                              \
    __builtin_amdgcn_s_setprio(1);                                             \
    MM_;                                                                       \
    __builtin_amdgcn_s_setprio(0);                                             \
    asm volatile("s_waitcnt " VM ::: "memory");                                \
    __builtin_amdgcn_s_barrier();                                              \
  }

  // One K-tile = 2 phases; stages tile T+2 into buf (T+2)%3.
#define TILE(T, BT, BT2, G, VM)                                                \
  {                                                                            \
    float s_ = wsv[(T)];                                                       \
    PH(RD_B(BT); RD_A(BT, 0), STG_A(G, BT2, (T) + 2), MMF(0, s_))              \
    PHW(RD_A(BT, 1), STG_B(G, BT2, (T) + 2), MMF(1, s_), VM)                   \
  }

  // prologue: stage tile0 -> buf0 (A 4 + B 2), tile1 -> buf1 (A 4 + B 2);
  // vmcnt(6) completes tile0's 6 (oldest), leaves tile1's 6 = steady
  // invariant; barrier publishes.
  STG_A(true, 0, 0);
  STG_B(true, 0, 0);
  STG_A(true, 49152, 1);
  STG_B(true, 49152, 1);
  asm volatile("s_waitcnt vmcnt(6)" ::: "memory");
  __builtin_amdgcn_s_barrier();

  // main loop: tiles 0..KB-3 (KB=32 -> t=0,3,...,27 covering 0..29),
  // every tile stages T+2 (<= KB-1) and waits vmcnt(6).
  for (int t = 0; t < KB - 2; t += 3) {
    TILE(t,     0,     98304, true, "vmcnt(6)")
    TILE(t + 1, 49152, 0,     true, "vmcnt(6)")
    TILE(t + 2, 98304, 49152, true, "vmcnt(6)")
  }
  // tail: tiles KB-2 (buf0), KB-1 (buf1); no staging; drain.
  TILE(KB - 2, 0,     98304, false, "vmcnt(0)")
  TILE(KB - 1, 49152, 0,     false, "vmcnt(0)")

#undef TILE
#undef PHW
#undef PH
#undef MMF
#undef RD_B
#undef RD_A
#undef STG_B
#undef STG_A
#undef GL

  // epilogue (validated C/D mapping): col=l31, row=q*8+hi2*4+j
#pragma unroll
  for (int mj = 0; mj < 2; ++mj)
#pragma unroll
    for (int nj = 0; nj < 2; ++nj) {
      int col = n0 + wc * 64 + nj * 32 + l31;
#pragma unroll
      for (int q = 0; q < 4; ++q) {
        int row0 = m0 + wr * 64 + mj * 32 + q * 8 + hi2 * 4;
        f32x4 sv = *(const f32x4*)(xs + row0);
#pragma unroll
        for (int j = 0; j < 4; ++j)
          Y[(size_t)(row0 + j) * N + col] = acc[mj][nj][q * 4 + j] * sv[j];
      }
    }
}

// ---------------------------------------------------------------------------
extern "C" void kernel_launch(void* const* d_in, const int* in_sizes, int n_in,
                              void* d_out, int out_size, void* d_ws, size_t ws_size,
                              hipStream_t stream) {
  const float* x     = (const float*)d_in[0];   // [B,S,K] f32
  const float* w     = (const float*)d_in[1];   // [N,K] f32 (fp8-representable)
  const float* wsinv = (const float*)d_in[2];   // [N/128,K/128] f32
  float* y = (float*)d_out;

  const int K = 4096;
  const int M = in_sizes[0] / K;   // 4096
  const int N = in_sizes[1] / K;   // 8192

  unsigned char* x8 = (unsigned char*)d_ws;                       // M*K
  float* xs = (float*)((char*)d_ws + (size_t)M * K);              // M floats
  unsigned char* w8 =
      (unsigned char*)d_ws + (size_t)M * K + (size_t)M * 4;       // N*K

  quant_x_fp8_kernel<<<M, 256, 0, stream>>>(x, x8, xs, K);
  quant_w_fp8_kernel<<<(int)(((size_t)N * K / 16 + 255) / 256), 256, 0,
                       stream>>>(w, w8);

  dim3 grid((M / 256) * (N / 128));  // 1024
  gemm_mxfp8_kernel<<<grid, 512, 0, stream>>>(x8, w8, xs, wsinv, y, M, N, K);
}

// Round 4
// 239.909 us; speedup vs baseline: 4.2420x; 2.7829x over previous
//
#include <hip/hip_runtime.h>

typedef float f32x4  __attribute__((ext_vector_type(4)));
typedef float f32x16 __attribute__((ext_vector_type(16)));
typedef int   i32x4  __attribute__((ext_vector_type(4)));
typedef int   i32x8  __attribute__((ext_vector_type(8)));

#define AS1 __attribute__((address_space(1)))
#define AS3 __attribute__((address_space(3)))

// ---------------------------------------------------------------------------
// Kernel 1 (R1, proven): per-token quant of x -> fp8 e4m3 + scale
// ---------------------------------------------------------------------------
__global__ __launch_bounds__(256) void quant_x_fp8_kernel(
    const float* __restrict__ x, unsigned char* __restrict__ x8,
    float* __restrict__ xs, int K) {
  int m = blockIdx.x;
  int t = threadIdx.x;
  const f32x4* src = (const f32x4*)(x + (size_t)m * K + t * 16);
  f32x4 v[4];
  float am = 0.0f;
#pragma unroll
  for (int i = 0; i < 4; ++i) {
    v[i] = src[i];
#pragma unroll
    for (int j = 0; j < 4; ++j) am = fmaxf(am, __builtin_fabsf(v[i][j]));
  }
#pragma unroll
  for (int off = 32; off >= 1; off >>= 1)
    am = fmaxf(am, __shfl_xor(am, off, 64));
  __shared__ float red[4];
  int wv = t >> 6, lane = t & 63;
  if (lane == 0) red[wv] = am;
  __syncthreads();
  am = fmaxf(fmaxf(red[0], red[1]), fmaxf(red[2], red[3]));
  am = fmaxf(am, 1e-12f);
  float sc = am / 448.0f;
  if (t == 0) xs[m] = sc;
  i32x4 out;
#pragma unroll
  for (int i = 0; i < 4; ++i) {
    float q0 = v[i][0] / sc, q1 = v[i][1] / sc;
    float q2 = v[i][2] / sc, q3 = v[i][3] / sc;
    int p = __builtin_amdgcn_cvt_pk_fp8_f32(q0, q1, 0, false);
    p = __builtin_amdgcn_cvt_pk_fp8_f32(q2, q3, p, true);
    out[i] = p;
  }
  *(i32x4*)(x8 + (size_t)m * K + t * 16) = out;
}

// ---------------------------------------------------------------------------
// Kernel 2 (R1, proven): weight f32 (fp8-representable) -> fp8 bytes
// ---------------------------------------------------------------------------
__global__ __launch_bounds__(256) void quant_w_fp8_kernel(
    const float* __restrict__ w, unsigned char* __restrict__ w8) {
  size_t idx = (size_t)blockIdx.x * 256 + threadIdx.x;
  const f32x4* src = (const f32x4*)w + idx * 4;
  i32x4 out;
#pragma unroll
  for (int i = 0; i < 4; ++i) {
    f32x4 v = src[i];
    int p = __builtin_amdgcn_cvt_pk_fp8_f32(v[0], v[1], 0, false);
    p = __builtin_amdgcn_cvt_pk_fp8_f32(v[2], v[3], p, true);
    out[i] = p;
  }
  ((i32x4*)w8)[idx] = out;
}

// ---------------------------------------------------------------------------
// Kernel 3: MX-fp8 GEMM. R16 = R12 geometry + A-triple/B-double pipeline,
// register-economical addressing.
// R15 post-mortem: 3x48KB bufs spilled ~12 VGPRs (WRITE 858MB vs Y's 134MB
// = scratch; scratch ops share the in-order vmcnt queue -> compiler waits
// for reloads drained the staging pipeline -> MfmaUtil 1-5%). Cause: the
// 3x-instantiated TILE macro kept 3 LDS address sets (~140 VGPR nominal vs
// 128 cap). Also LDS 147456 > 128KB (first occupancy collapse; 131072 was
// fine in R13/R14).
// R16: A gets 3 buffers (A was the pole: 2-buf caps its stage->consume at
// 1 phase), B keeps 2 -> LDS = 3*32KB + 2*16KB = 131072 exactly. Shared
// per-lane anchors (4 A + 4 B) + runtime SGPR rotating bases (s_cselect /
// s_xor) + "#pragma unroll 1" prevent address-set replication: nominal
// demand ~= R12's proven-fit level. launch_bounds(512,1) for headroom
// (R14: harmless).
// Geometry (R12-proven): block 256(M)x128(N), K-tile 128 (= scale block),
// 8 waves 4(wr)x2(wc), wave 64x64 -> acc[2][2] f32x16 = 64 VGPR.
// LDS map: A0@0 A1@32768 A2@65536 (32KB each), B0@98304 B1@114688 (16KB).
// Swizzle (validated): 16B slot s at row r stored s^(r&7); inverse applied
// on global source (rule #21).
// Per K-tile T (reads A-buf T%3 = rdA, B-buf T%2 = rdB), 2 phases:
//   P_A: RD_B + RD_A(mj0) | stage A(T+2)->stA=(T+2)%3 | bar | MMF(0) | bar
//   P_B: RD_A(mj1)        | stage B(T+2)->rdB (=T%2)  | bar | MMF(1) |
//        vmcnt(6) | bar
// WAR legality: A(T+2) overwrites A(T-1), last read P_B(T-1) pre-barrier;
// stage issues P_A(T) = 1 closing barrier later ok. B(T+2) overwrites B(T),
// last read P_A(T) pre-barrier; stage issues P_B(T) = 1 barrier later ok.
// vmcnt: steady outstanding after wait = {A(T+2):4, B(T+2):2} = 6; wait at
// P_B(T) completes {A(T+1), B(T+1)} before their publish barrier. Cover:
// A = 3 phases (~1100cy > ~900cy HBM miss), B = 2 phases (~750cy).
// Tail (KB-2, KB-1): no staging; vmcnt(0) drains.
// ---------------------------------------------------------------------------
__global__ __launch_bounds__(512, 1) void gemm_mxfp8_kernel(
    const unsigned char* __restrict__ A8,   // [M][K] fp8
    const unsigned char* __restrict__ W8,   // [N][K] fp8
    const float* __restrict__ xs,           // [M]
    const float* __restrict__ wsinv,        // [N/128][K/128]
    float* __restrict__ Y,                  // [M][N] f32
    int M, int N, int K) {
  const int KB = K >> 7;  // K/128 tiles (32)

  int bid = blockIdx.x, nwg = gridDim.x;
  int wg = (bid & 7) * (nwg >> 3) + (bid >> 3);
  int mt = M >> 8;                  // 16
  int bm = wg & (mt - 1);
  int bn = wg / mt;
  int m0 = bm << 8, n0 = bn << 7;   // 256 x 128 tile

  __shared__ __align__(16) char lds[131072];

  const int tid = threadIdx.x, wv = tid >> 6, lane = tid & 63;
  const int wr = wv >> 1, wc = wv & 1;          // 4 x 2 wave grid
  const int l31 = lane & 31, hi2 = lane >> 5;
  const int salt = l31 & 7;

  // per-lane slot offsets (validated swizzle)
  const int sL0 = ((hi2 * 2 + 0) ^ salt) << 4;       // ks=0, k-low 16B
  const int sH0 = ((hi2 * 2 + 1) ^ salt) << 4;       // ks=0, k-high
  const int sL1 = ((4 + hi2 * 2 + 0) ^ salt) << 4;   // ks=1
  const int sH1 = ((4 + hi2 * 2 + 1) ^ salt) << 4;

  // shared per-lane anchors (region base added at runtime via SGPR)
  const int aRow = (wr * 64 + l31) * 128;
  const int bRow = (wc * 64 + l31) * 128;
  const int aL0 = aRow + sL0, aH0 = aRow + sH0;
  const int aL1 = aRow + sL1, aH1 = aRow + sH1;
  const int bL0 = bRow + sL0, bH0 = bRow + sH0;
  const int bL1 = bRow + sL1, bH1 = bRow + sH1;

  // staging: dest = region + sweep*8192 + tid*16 (linear, 64 rows/sweep);
  // source row = sweep*64 + (tid>>3); col pre-swizzled (involution).
  const int stgD = tid << 4;
  const int rIdx = tid >> 3;
  const int cSrc = ((tid & 7) ^ ((tid >> 3) & 7)) << 4;
  const size_t rowB = (size_t)K;  // fp8: 1 byte/elem
  const size_t g64 = 64 * rowB;
  const char* pA = (const char*)A8 + (size_t)(m0 + rIdx) * rowB + cSrc;
  const char* pB = (const char*)W8 + (size_t)(n0 + rIdx) * rowB + cSrc;

  const float* wsv = wsinv + (size_t)bn * KB;  // block-uniform scale row

  f32x16 acc[2][2];
#pragma unroll
  for (int i = 0; i < 2; ++i)
#pragma unroll
    for (int j = 0; j < 2; ++j) acc[i][j] = (f32x16)0.0f;

  i32x8 af[2], bf[2][2];

#define GL(SRC, DST)                                                           \
  __builtin_amdgcn_global_load_lds((const AS1 void*)(SRC), (AS3 void*)(DST),   \
                                   16, 0, 0)
#define STG_A(COND, SB, SRC)                                                   \
  if (COND) {                                                                  \
    const char* s_ = (SRC);                                                    \
    char* d_ = lds + (SB) + stgD;                                              \
    GL(s_, d_);                                                                \
    GL(s_ + g64, d_ + 8192);                                                   \
    GL(s_ + 2 * g64, d_ + 16384);                                              \
    GL(s_ + 3 * g64, d_ + 24576);                                              \
  }
#define STG_B(COND, SB, SRC)                                                   \
  if (COND) {                                                                  \
    const char* s_ = (SRC);                                                    \
    char* d_ = lds + (SB) + stgD;                                              \
    GL(s_, d_);                                                                \
    GL(s_ + g64, d_ + 8192);                                                   \
  }

// A frags for one mj (both ksteps), runtime region base RB: 4 ds_read_b128
#define RD_A(RB, MJ)                                                           \
  {                                                                            \
    const char* p_ = lds + (RB) + (MJ) * 4096;                                 \
    i32x4 lo0 = *(const i32x4*)(p_ + aL0);                                     \
    i32x4 hi0 = *(const i32x4*)(p_ + aH0);                                     \
    i32x4 lo1 = *(const i32x4*)(p_ + aL1);                                     \
    i32x4 hi1 = *(const i32x4*)(p_ + aH1);                                     \
    af[0] = __builtin_shufflevector(lo0, hi0, 0, 1, 2, 3, 4, 5, 6, 7);         \
    af[1] = __builtin_shufflevector(lo1, hi1, 0, 1, 2, 3, 4, 5, 6, 7);         \
  }
// all B frags (nj 0..1 x ks 0..1), runtime region base RB: 8 ds_read_b128
#define RD_B(RB)                                                               \
  _Pragma("unroll") for (int nj = 0; nj < 2; ++nj) {                           \
    const char* p_ = lds + (RB) + nj * 4096;                                   \
    i32x4 lo0 = *(const i32x4*)(p_ + bL0);                                     \
    i32x4 hi0 = *(const i32x4*)(p_ + bH0);                                     \
    i32x4 lo1 = *(const i32x4*)(p_ + bL1);                                     \
    i32x4 hi1 = *(const i32x4*)(p_ + bH1);                                     \
    bf[nj][0] = __builtin_shufflevector(lo0, hi0, 0, 1, 2, 3, 4, 5, 6, 7);     \
    bf[nj][1] = __builtin_shufflevector(lo1, hi1, 0, 1, 2, 3, 4, 5, 6, 7);     \
  }

// 4 MFMA (2 nj x ks-chain) + fold by SV into acc[MJ][*]
#define MMF(MJ, SV)                                                            \
  _Pragma("unroll") for (int nj = 0; nj < 2; ++nj) {                           \
    f32x16 t_ = __builtin_amdgcn_mfma_scale_f32_32x32x64_f8f6f4(               \
        af[0], bf[nj][0], (f32x16)0.0f, 0, 0, 0, 0x7f7f7f7f, 0, 0x7f7f7f7f);   \
    t_ = __builtin_amdgcn_mfma_scale_f32_32x32x64_f8f6f4(                      \
        af[1], bf[nj][1], t_, 0, 0, 0, 0x7f7f7f7f, 0, 0x7f7f7f7f);             \
    _Pragma("unroll") for (int q = 0; q < 16; ++q)                             \
        acc[MJ][nj][q] = __builtin_fmaf(SV, t_[q], acc[MJ][nj][q]);            \
  }

  // prologue: A(0)->A0, B(0)->B0, A(1)->A1, B(1)->B1 (12 gloads);
  // vmcnt(6) completes tile0's 6, leaves tile1's 6 = steady invariant.
  STG_A(true, 0, pA);
  STG_B(true, 98304, pB);
  STG_A(true, 32768, pA + 128);
  STG_B(true, 114688, pB + 128);
  asm volatile("s_waitcnt vmcnt(6)" ::: "memory");
  __builtin_amdgcn_s_barrier();

  // rotating region bases (wave-uniform scalars) + rolling stage sources
  int rdA = 0;          // A-buf of tile T: {0,32768,65536} cycle
  int stA = 65536;      // A-buf of tile T+2
  int rdB = 98304;      // B-buf of tile T (= stage dest of B(T+2)): ^=16384
  const char* pAs = pA + 256;  // A source col of tile T+2
  const char* pBs = pB + 256;

#define TILE(T, G, VM)                                                         \
  {                                                                            \
    float s_ = wsv[(T)];                                                       \
    RD_B(rdB);                                                                 \
    RD_A(rdA, 0);                                                              \
    STG_A(G, stA, pAs);                                                        \
    __builtin_amdgcn_s_barrier();                                              \
    __builtin_amdgcn_s_setprio(1);                                             \
    MMF(0, s_);                                                                \
    __builtin_amdgcn_s_setprio(0);                                             \
    __builtin_amdgcn_s_barrier();                                              \
    RD_A(rdA, 1);                                                              \
    STG_B(G, rdB, pBs);                                                        \
    __builtin_amdgcn_s_barrier();                                              \
    __builtin_amdgcn_s_setprio(1);                                             \
    MMF(1, s_);                                                                \
    __builtin_amdgcn_s_setprio(0);                                             \
    asm volatile("s_waitcnt " VM ::: "memory");                                \
    __builtin_amdgcn_s_barrier();                                              \
    rdA = (rdA == 65536) ? 0 : rdA + 32768;                                    \
    stA = (stA == 65536) ? 0 : stA + 32768;                                    \
    rdB ^= 16384;                                                              \
    pAs += 128;                                                                \
    pBs += 128;                                                                \
  }

#pragma unroll 1
  for (int t = 0; t < KB - 2; ++t) {
    TILE(t, true, "vmcnt(6)")
  }
  // tail: tiles KB-2, KB-1; no staging; drain before last reads.
  TILE(KB - 2, false, "vmcnt(0)")
  TILE(KB - 1, false, "vmcnt(0)")

#undef TILE
#undef MMF
#undef RD_B
#undef RD_A
#undef STG_B
#undef STG_A
#undef GL

  // epilogue (validated C/D mapping): col=l31, row=q*8+hi2*4+j
#pragma unroll
  for (int mj = 0; mj < 2; ++mj)
#pragma unroll
    for (int nj = 0; nj < 2; ++nj) {
      int col = n0 + wc * 64 + nj * 32 + l31;
#pragma unroll
      for (int q = 0; q < 4; ++q) {
        int row0 = m0 + wr * 64 + mj * 32 + q * 8 + hi2 * 4;
        f32x4 sv = *(const f32x4*)(xs + row0);
#pragma unroll
        for (int j = 0; j < 4; ++j)
          Y[(size_t)(row0 + j) * N + col] = acc[mj][nj][q * 4 + j] * sv[j];
      }
    }
}

// ---------------------------------------------------------------------------
extern "C" void kernel_launch(void* const* d_in, const int* in_sizes, int n_in,
                              void* d_out, int out_size, void* d_ws, size_t ws_size,
                              hipStream_t stream) {
  const float* x     = (const float*)d_in[0];   // [B,S,K] f32
  const float* w     = (const float*)d_in[1];   // [N,K] f32 (fp8-representable)
  const float* wsinv = (const float*)d_in[2];   // [N/128,K/128] f32
  float* y = (float*)d_out;

  const int K = 4096;
  const int M = in_sizes[0] / K;   // 4096
  const int N = in_sizes[1] / K;   // 8192

  unsigned char* x8 = (unsigned char*)d_ws;                       // M*K
  float* xs = (float*)((char*)d_ws + (size_t)M * K);              // M floats
  unsigned char* w8 =
      (unsigned char*)d_ws + (size_t)M * K + (size_t)M * 4;       // N*K

  quant_x_fp8_kernel<<<M, 256, 0, stream>>>(x, x8, xs, K);
  quant_w_fp8_kernel<<<(int)(((size_t)N * K / 16 + 255) / 256), 256, 0,
                       stream>>>(w, w8);

  dim3 grid((M / 256) * (N / 128));  // 1024
  gemm_mxfp8_kernel<<<grid, 512, 0, stream>>>(x8, w8, xs, wsinv, y, M, N, K);
}

// Round 5
// 230.567 us; speedup vs baseline: 4.4139x; 1.0405x over previous
//
#include <hip/hip_runtime.h>

typedef float f32x4  __attribute__((ext_vector_type(4)));
typedef float f32x16 __attribute__((ext_vector_type(16)));
typedef int   i32x4  __attribute__((ext_vector_type(4)));
typedef int   i32x8  __attribute__((ext_vector_type(8)));

#define AS1 __attribute__((address_space(1)))
#define AS3 __attribute__((address_space(3)))

// ---------------------------------------------------------------------------
// Kernel 1 (R1, proven): per-token quant of x -> fp8 e4m3 + scale
// ---------------------------------------------------------------------------
__global__ __launch_bounds__(256) void quant_x_fp8_kernel(
    const float* __restrict__ x, unsigned char* __restrict__ x8,
    float* __restrict__ xs, int K) {
  int m = blockIdx.x;
  int t = threadIdx.x;
  const f32x4* src = (const f32x4*)(x + (size_t)m * K + t * 16);
  f32x4 v[4];
  float am = 0.0f;
#pragma unroll
  for (int i = 0; i < 4; ++i) {
    v[i] = src[i];
#pragma unroll
    for (int j = 0; j < 4; ++j) am = fmaxf(am, __builtin_fabsf(v[i][j]));
  }
#pragma unroll
  for (int off = 32; off >= 1; off >>= 1)
    am = fmaxf(am, __shfl_xor(am, off, 64));
  __shared__ float red[4];
  int wv = t >> 6, lane = t & 63;
  if (lane == 0) red[wv] = am;
  __syncthreads();
  am = fmaxf(fmaxf(red[0], red[1]), fmaxf(red[2], red[3]));
  am = fmaxf(am, 1e-12f);
  float sc = am / 448.0f;
  if (t == 0) xs[m] = sc;
  i32x4 out;
#pragma unroll
  for (int i = 0; i < 4; ++i) {
    float q0 = v[i][0] / sc, q1 = v[i][1] / sc;
    float q2 = v[i][2] / sc, q3 = v[i][3] / sc;
    int p = __builtin_amdgcn_cvt_pk_fp8_f32(q0, q1, 0, false);
    p = __builtin_amdgcn_cvt_pk_fp8_f32(q2, q3, p, true);
    out[i] = p;
  }
  *(i32x4*)(x8 + (size_t)m * K + t * 16) = out;
}

// ---------------------------------------------------------------------------
// Kernel 2 (R1, proven): weight f32 (fp8-representable) -> fp8 bytes
// ---------------------------------------------------------------------------
__global__ __launch_bounds__(256) void quant_w_fp8_kernel(
    const float* __restrict__ w, unsigned char* __restrict__ w8) {
  size_t idx = (size_t)blockIdx.x * 256 + threadIdx.x;
  const f32x4* src = (const f32x4*)w + idx * 4;
  i32x4 out;
#pragma unroll
  for (int i = 0; i < 4; ++i) {
    f32x4 v = src[i];
    int p = __builtin_amdgcn_cvt_pk_fp8_f32(v[0], v[1], 0, false);
    p = __builtin_amdgcn_cvt_pk_fp8_f32(v[2], v[3], p, true);
    out[i] = p;
  }
  ((i32x4*)w8)[idx] = out;
}

// ---------------------------------------------------------------------------
// Kernel 3: MX-fp8 GEMM. R17 = R16 minus intra-tile barriers (1 barrier/tile).
// R16 post-mortem: 3-deep pipe + no spill (VGPR 88, WRITE exactly Y) but dur
// UNCHANGED (192us, MfmaUtil 30%) -> stall was never load latency. Cycle
// audit: LDS reads 128KB (~1540cy) + stage writes (~380cy) vs MFMA 1100cy
// per K-tile per CU; measured 3600cy -> the 4 barriers/K-tile serialize the
// LDS and MFMA pipes (all 8 waves lockstep: read|bar|MFMA|bar). Fix: with
// 3-deep A AND B (3x32KB + 3x16KB = 144KB), stage(T+2) overwrites buf of
// T-1 whose last read preceded the tile-T barrier -> ONE barrier per tile
// is formally race-free. Inside the tile body waves skew freely: 2 waves/
// SIMD co-schedule ds_read and MFMA (m114 mechanism). Stages issue at tile
// top: cover ~1.7 tiles (~4500cy). Registers/math/swizzle/epilogue = R16.
// Geometry (R12-proven): block 256(M)x128(N), K-tile 128 (= scale block),
// 8 waves 4(wr)x2(wc), wave 64x64 -> acc[2][2] f32x16 = 64 VGPR.
// LDS map: A0@0 A1@32768 A2@65536; B0@98304 B1@114688 B2@131072 (147456).
// Swizzle (validated): 16B slot s at row r stored s^(r&7); inverse applied
// on global source (rule #21).
// Per K-tile T (bufs T%3): [tile body] RD_B,RD_A0 | stage A(T+2),B(T+2) |
// MFMA0 | RD_A1 | MFMA1 | vmcnt(6) | barrier.
// vmcnt: at end of T outstanding = T+1's 6 + T+2's 6 = 12; vmcnt(6)
// completes all of T+1 before its publish barrier. WAR: stage(T+2) hits
// buf (T-1)%3, last read in tile T-1 body, >= 1 barrier earlier ✓.
// Tail (KB-2, KB-1): no staging; vmcnt(0).
// ---------------------------------------------------------------------------
__global__ __launch_bounds__(512, 1) void gemm_mxfp8_kernel(
    const unsigned char* __restrict__ A8,   // [M][K] fp8
    const unsigned char* __restrict__ W8,   // [N][K] fp8
    const float* __restrict__ xs,           // [M]
    const float* __restrict__ wsinv,        // [N/128][K/128]
    float* __restrict__ Y,                  // [M][N] f32
    int M, int N, int K) {
  const int KB = K >> 7;  // K/128 tiles (32)

  int bid = blockIdx.x, nwg = gridDim.x;
  int wg = (bid & 7) * (nwg >> 3) + (bid >> 3);
  int mt = M >> 8;                  // 16
  int bm = wg & (mt - 1);
  int bn = wg / mt;
  int m0 = bm << 8, n0 = bn << 7;   // 256 x 128 tile

  __shared__ __align__(16) char lds[147456];

  const int tid = threadIdx.x, wv = tid >> 6, lane = tid & 63;
  const int wr = wv >> 1, wc = wv & 1;          // 4 x 2 wave grid
  const int l31 = lane & 31, hi2 = lane >> 5;
  const int salt = l31 & 7;

  // per-lane slot offsets (validated swizzle)
  const int sL0 = ((hi2 * 2 + 0) ^ salt) << 4;       // ks=0, k-low 16B
  const int sH0 = ((hi2 * 2 + 1) ^ salt) << 4;       // ks=0, k-high
  const int sL1 = ((4 + hi2 * 2 + 0) ^ salt) << 4;   // ks=1
  const int sH1 = ((4 + hi2 * 2 + 1) ^ salt) << 4;

  // shared per-lane anchors (region base added at runtime)
  const int aRow = (wr * 64 + l31) * 128;
  const int bRow = (wc * 64 + l31) * 128;
  const int aL0 = aRow + sL0, aH0 = aRow + sH0;
  const int aL1 = aRow + sL1, aH1 = aRow + sH1;
  const int bL0 = bRow + sL0, bH0 = bRow + sH0;
  const int bL1 = bRow + sL1, bH1 = bRow + sH1;

  // staging: dest = region + sweep*8192 + tid*16 (linear, 64 rows/sweep);
  // source row = sweep*64 + (tid>>3); col pre-swizzled (involution).
  const int stgD = tid << 4;
  const int rIdx = tid >> 3;
  const int cSrc = ((tid & 7) ^ ((tid >> 3) & 7)) << 4;
  const size_t rowB = (size_t)K;  // fp8: 1 byte/elem
  const size_t g64 = 64 * rowB;
  const char* pA = (const char*)A8 + (size_t)(m0 + rIdx) * rowB + cSrc;
  const char* pB = (const char*)W8 + (size_t)(n0 + rIdx) * rowB + cSrc;

  const float* wsv = wsinv + (size_t)bn * KB;  // block-uniform scale row

  f32x16 acc[2][2];
#pragma unroll
  for (int i = 0; i < 2; ++i)
#pragma unroll
    for (int j = 0; j < 2; ++j) acc[i][j] = (f32x16)0.0f;

  i32x8 af[2], bf[2][2];

#define GL(SRC, DST)                                                           \
  __builtin_amdgcn_global_load_lds((const AS1 void*)(SRC), (AS3 void*)(DST),   \
                                   16, 0, 0)
#define STG_A(COND, SB, SRC)                                                   \
  if (COND) {                                                                  \
    const char* s_ = (SRC);                                                    \
    char* d_ = lds + (SB) + stgD;                                              \
    GL(s_, d_);                                                                \
    GL(s_ + g64, d_ + 8192);                                                   \
    GL(s_ + 2 * g64, d_ + 16384);                                              \
    GL(s_ + 3 * g64, d_ + 24576);                                              \
  }
#define STG_B(COND, SB, SRC)                                                   \
  if (COND) {                                                                  \
    const char* s_ = (SRC);                                                    \
    char* d_ = lds + (SB) + stgD;                                              \
    GL(s_, d_);                                                                \
    GL(s_ + g64, d_ + 8192);                                                   \
  }

// A frags for one mj (both ksteps), runtime region base RB: 4 ds_read_b128
#define RD_A(RB, MJ)                                                           \
  {                                                                            \
    const char* p_ = lds + (RB) + (MJ) * 4096;                                 \
    i32x4 lo0 = *(const i32x4*)(p_ + aL0);                                     \
    i32x4 hi0 = *(const i32x4*)(p_ + aH0);                                     \
    i32x4 lo1 = *(const i32x4*)(p_ + aL1);                                     \
    i32x4 hi1 = *(const i32x4*)(p_ + aH1);                                     \
    af[0] = __builtin_shufflevector(lo0, hi0, 0, 1, 2, 3, 4, 5, 6, 7);         \
    af[1] = __builtin_shufflevector(lo1, hi1, 0, 1, 2, 3, 4, 5, 6, 7);         \
  }
// all B frags (nj 0..1 x ks 0..1), runtime region base RB: 8 ds_read_b128
#define RD_B(RB)                                                               \
  _Pragma("unroll") for (int nj = 0; nj < 2; ++nj) {                           \
    const char* p_ = lds + (RB) + nj * 4096;                                   \
    i32x4 lo0 = *(const i32x4*)(p_ + bL0);                                     \
    i32x4 hi0 = *(const i32x4*)(p_ + bH0);                                     \
    i32x4 lo1 = *(const i32x4*)(p_ + bL1);                                     \
    i32x4 hi1 = *(const i32x4*)(p_ + bH1);                                     \
    bf[nj][0] = __builtin_shufflevector(lo0, hi0, 0, 1, 2, 3, 4, 5, 6, 7);     \
    bf[nj][1] = __builtin_shufflevector(lo1, hi1, 0, 1, 2, 3, 4, 5, 6, 7);     \
  }

// 4 MFMA (2 nj x ks-chain) + fold by SV into acc[MJ][*]
#define MMF(MJ, SV)                                                            \
  _Pragma("unroll") for (int nj = 0; nj < 2; ++nj) {                           \
    f32x16 t_ = __builtin_amdgcn_mfma_scale_f32_32x32x64_f8f6f4(               \
        af[0], bf[nj][0], (f32x16)0.0f, 0, 0, 0, 0x7f7f7f7f, 0, 0x7f7f7f7f);   \
    t_ = __builtin_amdgcn_mfma_scale_f32_32x32x64_f8f6f4(                      \
        af[1], bf[nj][1], t_, 0, 0, 0, 0x7f7f7f7f, 0, 0x7f7f7f7f);             \
    _Pragma("unroll") for (int q = 0; q < 16; ++q)                             \
        acc[MJ][nj][q] = __builtin_fmaf(SV, t_[q], acc[MJ][nj][q]);            \
  }

  // prologue: A(0)->A0, B(0)->B0, A(1)->A1, B(1)->B1 (12 gloads);
  // vmcnt(6) completes tile0's 6, leaves tile1's 6 = steady invariant.
  STG_A(true, 0, pA);
  STG_B(true, 98304, pB);
  STG_A(true, 32768, pA + 128);
  STG_B(true, 114688, pB + 128);
  asm volatile("s_waitcnt vmcnt(6)" ::: "memory");
  __builtin_amdgcn_s_barrier();

  // rotating region bases (wave-uniform scalars) + rolling stage sources
  int rdA = 0;           // A-buf of tile T: {0,32768,65536} cycle
  int stA = 65536;       // A-buf of tile T+2
  int rdB = 98304;       // B-buf of tile T: {98304,114688,131072} cycle
  int stB = 131072;      // B-buf of tile T+2
  const char* pAs = pA + 256;  // A source col of tile T+2
  const char* pBs = pB + 256;

#define TILE(T, G, VM)                                                         \
  {                                                                            \
    float s_ = wsv[(T)];                                                       \
    RD_B(rdB);                                                                 \
    RD_A(rdA, 0);                                                              \
    STG_A(G, stA, pAs);                                                        \
    STG_B(G, stB, pBs);                                                        \
    __builtin_amdgcn_s_setprio(1);                                             \
    MMF(0, s_);                                                                \
    __builtin_amdgcn_s_setprio(0);                                             \
    RD_A(rdA, 1);                                                              \
    __builtin_amdgcn_s_setprio(1);                                             \
    MMF(1, s_);                                                                \
    __builtin_amdgcn_s_setprio(0);                                             \
    asm volatile("s_waitcnt " VM ::: "memory");                                \
    __builtin_amdgcn_s_barrier();                                              \
    rdA = (rdA == 65536) ? 0 : rdA + 32768;                                    \
    stA = (stA == 65536) ? 0 : stA + 32768;                                    \
    rdB = (rdB == 131072) ? 98304 : rdB + 16384;                               \
    stB = (stB == 131072) ? 98304 : stB + 16384;                               \
    pAs += 128;                                                                \
    pBs += 128;                                                                \
  }

#pragma unroll 1
  for (int t = 0; t < KB - 2; ++t) {
    TILE(t, true, "vmcnt(6)")
  }
  // tail: tiles KB-2, KB-1; no staging; drain before last reads.
  TILE(KB - 2, false, "vmcnt(0)")
  TILE(KB - 1, false, "vmcnt(0)")

#undef TILE
#undef MMF
#undef RD_B
#undef RD_A
#undef STG_B
#undef STG_A
#undef GL

  // epilogue (validated C/D mapping): col=l31, row=q*8+hi2*4+j
#pragma unroll
  for (int mj = 0; mj < 2; ++mj)
#pragma unroll
    for (int nj = 0; nj < 2; ++nj) {
      int col = n0 + wc * 64 + nj * 32 + l31;
#pragma unroll
      for (int q = 0; q < 4; ++q) {
        int row0 = m0 + wr * 64 + mj * 32 + q * 8 + hi2 * 4;
        f32x4 sv = *(const f32x4*)(xs + row0);
#pragma unroll
        for (int j = 0; j < 4; ++j)
          Y[(size_t)(row0 + j) * N + col] = acc[mj][nj][q * 4 + j] * sv[j];
      }
    }
}

// ---------------------------------------------------------------------------
extern "C" void kernel_launch(void* const* d_in, const int* in_sizes, int n_in,
                              void* d_out, int out_size, void* d_ws, size_t ws_size,
                              hipStream_t stream) {
  const float* x     = (const float*)d_in[0];   // [B,S,K] f32
  const float* w     = (const float*)d_in[1];   // [N,K] f32 (fp8-representable)
  const float* wsinv = (const float*)d_in[2];   // [N/128,K/128] f32
  float* y = (float*)d_out;

  const int K = 4096;
  const int M = in_sizes[0] / K;   // 4096
  const int N = in_sizes[1] / K;   // 8192

  unsigned char* x8 = (unsigned char*)d_ws;                       // M*K
  float* xs = (float*)((char*)d_ws + (size_t)M * K);              // M floats
  unsigned char* w8 =
      (unsigned char*)d_ws + (size_t)M * K + (size_t)M * 4;       // N*K

  quant_x_fp8_kernel<<<M, 256, 0, stream>>>(x, x8, xs, K);
  quant_w_fp8_kernel<<<(int)(((size_t)N * K / 16 + 255) / 256), 256, 0,
                       stream>>>(w, w8);

  dim3 grid((M / 256) * (N / 128));  // 1024
  gemm_mxfp8_kernel<<<grid, 512, 0, stream>>>(x8, w8, xs, wsinv, y, M, N, K);
}